// Round 8
// baseline (9686.803 us; speedup 1.0000x reference)
//
#include <hip/hip_runtime.h>
#include <hip/hip_bf16.h>
#include <hip/hip_fp16.h>

typedef _Float16 v2h __attribute__((ext_vector_type(2)));

__device__ __forceinline__ float fdot2u(unsigned int a, unsigned int b, float c){
  return __builtin_amdgcn_fdot2(__builtin_bit_cast(v2h, a), __builtin_bit_cast(v2h, b), c, false);
}
__device__ __forceinline__ unsigned int packh2(float a, float b){
  union{ _Float16 h[2]; unsigned int u; } z;
  z.h[0] = (_Float16)a; z.h[1] = (_Float16)b; return z.u;
}
__device__ __forceinline__ float h2f(unsigned short s){
  return (float)__builtin_bit_cast(_Float16, s);
}
__device__ __forceinline__ float sigf(float x){
  return __builtin_amdgcn_rcpf(1.0f + __builtin_amdgcn_exp2f(-1.44269504f*x));
}
__device__ __forceinline__ float tanhf_(float x){
  return 2.0f*__builtin_amdgcn_rcpf(1.0f + __builtin_amdgcn_exp2f(-2.88539008f*x)) - 1.0f;
}
// quad_perm [1,0,3,2]: swap lane pairs (p0<->p1) — pure VALU
__device__ __forceinline__ float dpp_xor1(float x){
  return __builtin_bit_cast(float,
    __builtin_amdgcn_mov_dpp(__builtin_bit_cast(int, x), 0xB1, 0xF, 0xF, true));
}

// ---------------- Kernel A: weight conversion (K-half chunk layout) + flag zero ----------------
// whhT3 uint4 index = (g*16+j)*512 + (u*2+p), dword l:
//   holds W_hh[g*256+u][k] pair for dword d = p*64 + j*4 + l (k = 2d, 2d+1).
__global__ void prep_kernel(const float* __restrict__ Whh, const float* __restrict__ Wfc,
                            const float* __restrict__ bih, const float* __restrict__ bhh,
                            unsigned int* __restrict__ whhT3, unsigned int* __restrict__ wfc16,
                            float* __restrict__ bsum, unsigned int* __restrict__ flags){
  int i = blockIdx.x*256 + threadIdx.x;
  if (i < 131072){                       // W_hh (1024 x 256) f32 -> f16 pair dwords
    int r = i >> 7, d = i & 127;
    int g = r >> 8, u = r & 255;
    int p = (d >> 6) & 1, j = (d >> 2) & 15, l = d & 3;
    whhT3[(size_t)((g*16+j)*512 + u*2 + p)*4 + l] = packh2(Whh[r*256 + 2*d], Whh[r*256 + 2*d + 1]);
  } else if (i < 139264){                // W_fc (64 x 256) -> (64 x 128)
    int j = i - 131072; int o = j >> 7, d = j & 127;
    wfc16[j] = packh2(Wfc[o*256 + 2*d], Wfc[o*256 + 2*d + 1]);
  } else if (i < 140288){                // bsum = b_ih + b_hh
    int g = i - 139264;
    bsum[g] = bih[g] + bhh[g];
  } else if (i < 140320){                // sync counters (one per batch), re-zeroed every launch
    flags[i - 140288] = 0u;
  }
}

// ---------------- Kernel B: x_proj = x @ W_ih^T + bsum (f16 out) ----------------
#define XS 68
__global__ __launch_bounds__(256) void xproj_kernel(const float* __restrict__ x,
                          const float* __restrict__ Wih,
                          const float* __restrict__ bsum, unsigned int* __restrict__ xproj){
  __shared__ unsigned int lx[128*XS];
  __shared__ unsigned int lw[64*XS];
  __shared__ float lb[64];
  int t  = threadIdx.x;
  int bt0 = blockIdx.x*128, g0 = blockIdx.y*64;
  int rr = t >> 4, cc = t & 15;
  #pragma unroll
  for (int it=0; it<8; ++it){
    int row = rr + it*16;
    const float4* s = (const float4*)(x + (size_t)(bt0+row)*128 + cc*8);
    float4 a = s[0], b = s[1];
    uint4 w; w.x=packh2(a.x,a.y); w.y=packh2(a.z,a.w); w.z=packh2(b.x,b.y); w.w=packh2(b.z,b.w);
    *(uint4*)&lx[row*XS + cc*4] = w;
  }
  #pragma unroll
  for (int it=0; it<4; ++it){
    int row = rr + it*16;
    const float4* s = (const float4*)(Wih + (size_t)(g0+row)*128 + cc*8);
    float4 a = s[0], b = s[1];
    uint4 w; w.x=packh2(a.x,a.y); w.y=packh2(a.z,a.w); w.z=packh2(b.x,b.y); w.w=packh2(b.z,b.w);
    *(uint4*)&lw[row*XS + cc*4] = w;
  }
  if (t < 64) lb[t] = bsum[g0 + t];
  __syncthreads();

  float acc[8][4];
  #pragma unroll
  for (int j=0;j<8;++j)
    #pragma unroll
    for (int i=0;i<4;++i) acc[j][i]=0.f;

  #pragma unroll
  for (int d4=0; d4<16; ++d4){
    uint4 wv[4], xv[8];
    #pragma unroll
    for (int i=0;i<4;++i) wv[i] = *(const uint4*)&lw[(cc*4+i)*XS + d4*4];
    #pragma unroll
    for (int j=0;j<8;++j) xv[j] = *(const uint4*)&lx[(rr*8+j)*XS + d4*4];
    #pragma unroll
    for (int j=0;j<8;++j){
      #pragma unroll
      for (int i=0;i<4;++i){
        float a = acc[j][i];
        a = fdot2u(xv[j].x, wv[i].x, a);
        a = fdot2u(xv[j].y, wv[i].y, a);
        a = fdot2u(xv[j].z, wv[i].z, a);
        a = fdot2u(xv[j].w, wv[i].w, a);
        acc[j][i] = a;
      }
    }
  }
  #pragma unroll
  for (int j=0;j<8;++j){
    int bt = bt0 + rr*8 + j;
    uint2 o2;
    o2.x = packh2(acc[j][0]+lb[cc*4+0], acc[j][1]+lb[cc*4+1]);
    o2.y = packh2(acc[j][2]+lb[cc*4+2], acc[j][3]+lb[cc*4+3]);
    *(uint2*)&xproj[(size_t)bt*512 + (g0>>1) + cc*2] = o2;
  }
}

// ---------------- Kernel C: recurrent LSTM — GATE-SPLIT across 4 CUs per batch ----------------
// Grid 128 = 32 batches x 4 gates. WG (b,gg) owns gate gg's 256x256 weight
// slice = 64 dwords/thread at 512 threads -> ALL in arch VGPRs (no AGPR tax,
// no LDS weight streaming). Thread t = u*2+p: unit u, K-half p.
// Per step: 64 fdot2/thread; DPP pair-reduce; store own gate acts (f32) to
// global; atomicAdd per-batch counter (release); t0 spins acquire until all
// 4 gates posted; load 4 acts; update c,h redundantly on all 4 CUs; publish
// h to own LDS (pad +4 dwords between K-halves -> conflict-free reads).
// Acts double-buffered by step parity (WAR-safe: a buffer is rewritten only
// after the spin proves all its readers advanced). Blocks {b,b+32,b+64,b+96}
// are congruent mod 8 -> same XCD under round-robin (perf-only assumption).
extern "C" __global__ void __launch_bounds__(512,2) lstm_kernel(
    const unsigned int* __restrict__ whhT3, const unsigned int* __restrict__ xproj,
    unsigned short* __restrict__ h_all, float* __restrict__ acts,
    unsigned int* __restrict__ flags)
{
  __shared__ unsigned int hlds[2][136];   // [buf][64 lower | pad4 | 64 upper | pad4]
  const int t = threadIdx.x;
  const int u = t >> 1, p = t & 1;
  const int wg = blockIdx.x;
  const int b = wg & 31, gg = wg >> 5;

  uint4 w4[16];
  {
    const uint4* wsrc = (const uint4*)whhT3;
    #pragma unroll
    for (int j=0; j<16; ++j) w4[j] = wsrc[(gg*16+j)*512 + t];
  }
  if (t < 136){ hlds[0][t] = 0u; hlds[1][t] = 0u; }

  const unsigned short* xpb = (const unsigned short*)xproj
                              + (size_t)b*2048*1024 + gg*256 + u;
  unsigned short xn = xpb[0];
  float c = 0.f;
  unsigned short* hout = h_all + (size_t)b*2048*256 + u;
  unsigned int* flg = flags + b;
  __syncthreads();

  for (int tt=0; tt<2048; ++tt){
    const int cur = tt & 1;
    float xv = h2f(xn);
    int tn = (tt+1 < 2048) ? tt+1 : 2047;
    xn = xpb[(size_t)tn*1024];

    const unsigned int* hb = &hlds[cur][p*68];
    float A0 = 0.f, A1 = 0.f;
    #pragma unroll
    for (int j=0; j<16; ++j){
      uint4 h4 = *(const uint4*)(hb + j*4);
      A0 = fdot2u(w4[j].x, h4.x, A0); A1 = fdot2u(w4[j].y, h4.y, A1);
      A0 = fdot2u(w4[j].z, h4.z, A0); A1 = fdot2u(w4[j].w, h4.w, A1);
    }
    float A = A0 + A1;
    A += dpp_xor1(A);                 // sum the two K-halves
    A += xv;
    float act = (gg == 2) ? tanhf_(A) : sigf(A);   // gg is WG-uniform

    float* ab = acts + ((size_t)b*2 + cur)*1024;
    if (p == 0) ab[gg*256 + u] = act; // plain store; drained by barrier below
    __syncthreads();                  // all stores vmcnt-drained (L1 write-through -> in L2)

    if (t == 0){
      __hip_atomic_fetch_add(flg, 1u, __ATOMIC_RELEASE, __HIP_MEMORY_SCOPE_AGENT);
      unsigned int target = 4u*(unsigned)(tt+1);
      while (__hip_atomic_fetch_add(flg, 0u, __ATOMIC_ACQUIRE, __HIP_MEMORY_SCOPE_AGENT) < target){
        __builtin_amdgcn_s_sleep(1);
      }
    }
    __syncthreads();                  // t0's acquire (L1 inv) ordered before loads below

    const float* ar = acts + ((size_t)b*2 + cur)*1024;
    float gi = ar[u];
    float gf = ar[256 + u];
    float g_ = ar[512 + u];
    float go = ar[768 + u];
    c = gf*c + gi*g_;
    float h = go * tanhf_(c);
    unsigned short hh = __builtin_bit_cast(unsigned short, (_Float16)h);
    if (p == 0){
      ((unsigned short*)hlds[cur^1])[(u < 128) ? u : (u + 8)] = hh;  // +8 halves = +4 dword pad
      if (gg == 0) hout[(size_t)tt*256] = hh;
    }
    __syncthreads();                  // h published before next step's reads
  }
}

// ---------------- Kernel D: logits = h @ W_fc^T + b_fc ; softmax over O=64 ----------------
__global__ __launch_bounds__(1024) void fc_softmax_kernel(const unsigned short* __restrict__ h_all,
      const unsigned int* __restrict__ wfc16, const float* __restrict__ bfc,
      float* __restrict__ out){
  __shared__ unsigned int lwf[64*132];
  __shared__ unsigned int lh[16*132];
  int t = threadIdx.x;
  int bt0 = blockIdx.x*16;
  {
    const uint4* s = (const uint4*)(wfc16 + (size_t)t*8);
    uint4 a = s[0], b = s[1];
    unsigned int* dst = &lwf[(t>>4)*132 + (t&15)*8];
    *(uint4*)dst = a; *(uint4*)(dst+4) = b;
  }
  {
    int row = t>>6, col = (t&63)*2;
    const unsigned int* hsrc = (const unsigned int*)h_all;
    uint2 v = *(const uint2*)(hsrc + (size_t)(bt0+row)*128 + col);
    *(uint2*)&lh[row*132 + col] = v;
  }
  __syncthreads();
  int w = t>>6, o = t&63;
  int bt = bt0 + w;
  float acc = bfc[o];
  #pragma unroll
  for (int d4=0; d4<32; ++d4){
    uint4 hq = *(const uint4*)&lh[w*132 + d4*4];
    uint4 wq = *(const uint4*)&lwf[o*132 + d4*4];
    acc = fdot2u(wq.x, hq.x, acc);
    acc = fdot2u(wq.y, hq.y, acc);
    acc = fdot2u(wq.z, hq.z, acc);
    acc = fdot2u(wq.w, hq.w, acc);
  }
  float m = acc;
  #pragma unroll
  for (int off=32; off>=1; off>>=1) m = fmaxf(m, __shfl_xor(m, off));
  float e = __builtin_amdgcn_exp2f(1.44269504f*(acc - m));
  float s = e;
  #pragma unroll
  for (int off=32; off>=1; off>>=1) s += __shfl_xor(s, off);
  out[(size_t)bt*64 + o] = e * __builtin_amdgcn_rcpf(s);
}

// ---------------- launch ----------------
extern "C" void kernel_launch(void* const* d_in, const int* in_sizes, int n_in,
                              void* d_out, int out_size, void* d_ws, size_t ws_size,
                              hipStream_t stream){
  const float* x   = (const float*)d_in[0];
  const float* Wih = (const float*)d_in[1];
  const float* Whh = (const float*)d_in[2];
  const float* bih = (const float*)d_in[3];
  const float* bhh = (const float*)d_in[4];
  const float* Wfc = (const float*)d_in[5];
  const float* bfc = (const float*)d_in[6];
  float* out = (float*)d_out;

  char* ws = (char*)d_ws;
  unsigned int*   xproj = (unsigned int*)ws;                         // 128 MB (f16 pairs)
  unsigned short* h_all = (unsigned short*)(ws + 134217728);         // 32 MB (f16)
  unsigned int*   whhT3 = (unsigned int*)(ws + 134217728 + 33554432);// 512 KB (chunked)
  unsigned int*   wfc16 = whhT3 + 131072;                            // 32 KB
  float*          bsum  = (float*)(wfc16 + 8192);                    // 4 KB
  unsigned int*   flags = (unsigned int*)(bsum + 1024);              // 128 B
  float*          acts  = (float*)(flags + 32);                      // 256 KB [b][par][g][u]

  prep_kernel<<<549, 256, 0, stream>>>(Whh, Wfc, bih, bhh, whhT3, wfc16, bsum, flags);
  dim3 gb(512, 16);
  xproj_kernel<<<gb, 256, 0, stream>>>(x, Wih, bsum, xproj);
  lstm_kernel<<<128, 512, 0, stream>>>(whhT3, xproj, h_all, acts, flags);
  fc_softmax_kernel<<<4096, 1024, 0, stream>>>(h_all, wfc16, bfc, out);
}

// Round 9
// 3577.061 us; speedup vs baseline: 2.7080x; 2.7080x over previous
//
#include <hip/hip_runtime.h>
#include <hip/hip_bf16.h>
#include <hip/hip_fp16.h>

typedef _Float16 v2h __attribute__((ext_vector_type(2)));

__device__ __forceinline__ float fdot2u(unsigned int a, unsigned int b, float c){
  return __builtin_amdgcn_fdot2(__builtin_bit_cast(v2h, a), __builtin_bit_cast(v2h, b), c, false);
}
__device__ __forceinline__ unsigned int packh2(float a, float b){
  union{ _Float16 h[2]; unsigned int u; } z;
  z.h[0] = (_Float16)a; z.h[1] = (_Float16)b; return z.u;
}
__device__ __forceinline__ float h2f(unsigned short s){
  return (float)__builtin_bit_cast(_Float16, s);
}
__device__ __forceinline__ float sigf(float x){
  return __builtin_amdgcn_rcpf(1.0f + __builtin_amdgcn_exp2f(-1.44269504f*x));
}
__device__ __forceinline__ float tanhf_(float x){
  return 2.0f*__builtin_amdgcn_rcpf(1.0f + __builtin_amdgcn_exp2f(-2.88539008f*x)) - 1.0f;
}

// ---------------- Kernel A: weight conversion (chunk-transposed) ----------------
// whhT uint4 index = q*1024 + r  (q=0..31 chunk, r=row): holds W_hh[r][k],
// k = 8q..8q+7 as 4 f16-pair dwords -> lane-coalesced loads for thread=row.
__global__ void prep_kernel(const float* __restrict__ Whh, const float* __restrict__ Wfc,
                            const float* __restrict__ bih, const float* __restrict__ bhh,
                            unsigned int* __restrict__ whhT, unsigned int* __restrict__ wfc16,
                            float* __restrict__ bsum){
  int i = blockIdx.x*256 + threadIdx.x;
  if (i < 131072){                       // W_hh (1024 x 256) f32 -> f16 pair dwords
    int r = i >> 7, d = i & 127;
    int q = d >> 2, l = d & 3;
    whhT[q*4096 + r*4 + l] = packh2(Whh[r*256 + 2*d], Whh[r*256 + 2*d + 1]);
  } else if (i < 139264){                // W_fc (64 x 256) -> (64 x 128)
    int j = i - 131072; int o = j >> 7, d = j & 127;
    wfc16[j] = packh2(Wfc[o*256 + 2*d], Wfc[o*256 + 2*d + 1]);
  } else if (i < 140288){                // bsum = b_ih + b_hh
    int g = i - 139264;
    bsum[g] = bih[g] + bhh[g];
  }
}

// ---------------- Kernel B: x_proj = x @ W_ih^T + bsum (f16 out) ----------------
#define XS 68
__global__ __launch_bounds__(256) void xproj_kernel(const float* __restrict__ x,
                          const float* __restrict__ Wih,
                          const float* __restrict__ bsum, unsigned int* __restrict__ xproj){
  __shared__ unsigned int lx[128*XS];
  __shared__ unsigned int lw[64*XS];
  __shared__ float lb[64];
  int t  = threadIdx.x;
  int bt0 = blockIdx.x*128, g0 = blockIdx.y*64;
  int rr = t >> 4, cc = t & 15;
  #pragma unroll
  for (int it=0; it<8; ++it){
    int row = rr + it*16;
    const float4* s = (const float4*)(x + (size_t)(bt0+row)*128 + cc*8);
    float4 a = s[0], b = s[1];
    uint4 w; w.x=packh2(a.x,a.y); w.y=packh2(a.z,a.w); w.z=packh2(b.x,b.y); w.w=packh2(b.z,b.w);
    *(uint4*)&lx[row*XS + cc*4] = w;
  }
  #pragma unroll
  for (int it=0; it<4; ++it){
    int row = rr + it*16;
    const float4* s = (const float4*)(Wih + (size_t)(g0+row)*128 + cc*8);
    float4 a = s[0], b = s[1];
    uint4 w; w.x=packh2(a.x,a.y); w.y=packh2(a.z,a.w); w.z=packh2(b.x,b.y); w.w=packh2(b.z,b.w);
    *(uint4*)&lw[row*XS + cc*4] = w;
  }
  if (t < 64) lb[t] = bsum[g0 + t];
  __syncthreads();

  float acc[8][4];
  #pragma unroll
  for (int j=0;j<8;++j)
    #pragma unroll
    for (int i=0;i<4;++i) acc[j][i]=0.f;

  #pragma unroll
  for (int d4=0; d4<16; ++d4){
    uint4 wv[4], xv[8];
    #pragma unroll
    for (int i=0;i<4;++i) wv[i] = *(const uint4*)&lw[(cc*4+i)*XS + d4*4];
    #pragma unroll
    for (int j=0;j<8;++j) xv[j] = *(const uint4*)&lx[(rr*8+j)*XS + d4*4];
    #pragma unroll
    for (int j=0;j<8;++j){
      #pragma unroll
      for (int i=0;i<4;++i){
        float a = acc[j][i];
        a = fdot2u(xv[j].x, wv[i].x, a);
        a = fdot2u(xv[j].y, wv[i].y, a);
        a = fdot2u(xv[j].z, wv[i].z, a);
        a = fdot2u(xv[j].w, wv[i].w, a);
        acc[j][i] = a;
      }
    }
  }
  #pragma unroll
  for (int j=0;j<8;++j){
    int bt = bt0 + rr*8 + j;
    uint2 o2;
    o2.x = packh2(acc[j][0]+lb[cc*4+0], acc[j][1]+lb[cc*4+1]);
    o2.y = packh2(acc[j][2]+lb[cc*4+2], acc[j][3]+lb[cc*4+3]);
    *(uint2*)&xproj[(size_t)bt*512 + (g0>>1) + cc*2] = o2;
  }
}

// ---------------- Kernel C: recurrent LSTM (R2 structure + 4-accum dep-break) ----------------
// 1024 threads/WG (4 waves/SIMD), 1 WG/batch. Thread t owns gate-row t
// (g = t>>8 wave-uniform, unit u = t&255), full K=256.
// Weights: 24 uint4 in regs + 8 uint4 streamed from LDS ([chunk][thread],
// conflict-free b128; base laundered vs LICM). h f16 in LDS, double-buffered,
// ALL reads wave-uniform broadcast. FOUR accumulators -> fdot2 reuse distance
// 8cy (tests the dependency-stall theory vs half-rate fdot2).
// Gate exchange via gbuf (f32, conflict-free). 2 barriers/step.
#define WRQ 24
#define WLQ 8
#define HOFF (WLQ*4096)            // dword offset of h double-buffer (2 x 128 dw)
#define GOFF (HOFF + 256)          // dword offset of gbuf (1024 f32)

extern "C" __global__ void __launch_bounds__(1024,4) lstm_kernel(
    const unsigned int* __restrict__ whhT, const unsigned int* __restrict__ xproj,
    unsigned short* __restrict__ h_all)
{
  extern __shared__ unsigned int lds[];
  uint4* lw4 = (uint4*)lds;
  unsigned short* lds16 = (unsigned short*)lds;
  float* gbuf = (float*)(lds + GOFF);
  const int t = threadIdx.x;
  const int g = t >> 8;            // wave-uniform gate index
  const int b = blockIdx.x;

  const uint4* wsrc = (const uint4*)whhT;
  uint4 w4[WRQ];
  #pragma unroll
  for (int q=0; q<WRQ; ++q) w4[q] = wsrc[q*1024 + t];
  #pragma unroll
  for (int q=0; q<WLQ; ++q) lw4[q*1024 + t] = wsrc[(WRQ+q)*1024 + t];
  if (t < 256) lds[HOFF + t] = 0u;     // zero both h buffers

  const unsigned short* xpb = (const unsigned short*)xproj + (size_t)b*2048*1024 + t;
  unsigned short xn = xpb[0];
  float c = 0.f;
  unsigned short* hout = h_all + (size_t)b*2048*256 + t;   // used only by t<256
  __syncthreads();

  for (int tt=0; tt<2048; ++tt){
    const int cur = tt & 1;
    float xv = h2f(xn);
    int tn = (tt+1 < 2048) ? tt+1 : 2047;
    xn = xpb[(size_t)tn*1024];

    const unsigned int* hb = lds + HOFF + cur*128;
    // launder LDS weight base: defeat LICM hoisting 32 dwords into registers
    int zoff = 0;
    asm volatile("" : "+v"(zoff));
    const uint4* lwl = lw4 + zoff;

    float A0=0.f, A1=0.f, A2=0.f, A3=0.f;   // 4 chains: reuse distance 8cy
    #pragma unroll
    for (int q=0; q<WRQ; ++q){
      uint4 h4 = *(const uint4*)(hb + q*4);
      A0 = fdot2u(w4[q].x, h4.x, A0);
      A1 = fdot2u(w4[q].y, h4.y, A1);
      A2 = fdot2u(w4[q].z, h4.z, A2);
      A3 = fdot2u(w4[q].w, h4.w, A3);
    }
    #pragma unroll
    for (int q=0; q<WLQ; ++q){
      uint4 wq = lwl[q*1024 + t];
      uint4 h4 = *(const uint4*)(hb + (WRQ+q)*4);
      A0 = fdot2u(wq.x, h4.x, A0);
      A1 = fdot2u(wq.y, h4.y, A1);
      A2 = fdot2u(wq.z, h4.z, A2);
      A3 = fdot2u(wq.w, h4.w, A3);
    }
    float A = ((A0+A1) + (A2+A3)) + xv;
    float act = (g == 2) ? tanhf_(A) : sigf(A);
    gbuf[t] = act;
    __syncthreads();

    if (t < 256){
      float gi = gbuf[t];
      float gf = gbuf[256 + t];
      float g_ = gbuf[512 + t];
      float go = gbuf[768 + t];
      c = gf*c + gi*g_;
      float h = go * tanhf_(c);
      unsigned short hh = __builtin_bit_cast(unsigned short, (_Float16)h);
      lds16[(HOFF + (cur^1)*128)*2 + t] = hh;   // next step's h
      hout[(size_t)tt*256] = hh;                // h_all for fc phase
    }
    __syncthreads();
  }
}

// ---------------- Kernel D: logits = h @ W_fc^T + b_fc ; softmax over O=64 ----------------
__global__ __launch_bounds__(1024) void fc_softmax_kernel(const unsigned short* __restrict__ h_all,
      const unsigned int* __restrict__ wfc16, const float* __restrict__ bfc,
      float* __restrict__ out){
  __shared__ unsigned int lwf[64*132];
  __shared__ unsigned int lh[16*132];
  int t = threadIdx.x;
  int bt0 = blockIdx.x*16;
  {
    const uint4* s = (const uint4*)(wfc16 + (size_t)t*8);
    uint4 a = s[0], b = s[1];
    unsigned int* dst = &lwf[(t>>4)*132 + (t&15)*8];
    *(uint4*)dst = a; *(uint4*)(dst+4) = b;
  }
  {
    int row = t>>6, col = (t&63)*2;
    const unsigned int* hsrc = (const unsigned int*)h_all;
    uint2 v = *(const uint2*)(hsrc + (size_t)(bt0+row)*128 + col);
    *(uint2*)&lh[row*132 + col] = v;
  }
  __syncthreads();
  int w = t>>6, o = t&63;
  int bt = bt0 + w;
  float acc = bfc[o];
  #pragma unroll
  for (int d4=0; d4<32; ++d4){
    uint4 hq = *(const uint4*)&lh[w*132 + d4*4];
    uint4 wq = *(const uint4*)&lwf[o*132 + d4*4];
    acc = fdot2u(wq.x, hq.x, acc);
    acc = fdot2u(wq.y, hq.y, acc);
    acc = fdot2u(wq.z, hq.z, acc);
    acc = fdot2u(wq.w, hq.w, acc);
  }
  float m = acc;
  #pragma unroll
  for (int off=32; off>=1; off>>=1) m = fmaxf(m, __shfl_xor(m, off));
  float e = __builtin_amdgcn_exp2f(1.44269504f*(acc - m));
  float s = e;
  #pragma unroll
  for (int off=32; off>=1; off>>=1) s += __shfl_xor(s, off);
  out[(size_t)bt*64 + o] = e * __builtin_amdgcn_rcpf(s);
}

// ---------------- launch ----------------
extern "C" void kernel_launch(void* const* d_in, const int* in_sizes, int n_in,
                              void* d_out, int out_size, void* d_ws, size_t ws_size,
                              hipStream_t stream){
  const float* x   = (const float*)d_in[0];
  const float* Wih = (const float*)d_in[1];
  const float* Whh = (const float*)d_in[2];
  const float* bih = (const float*)d_in[3];
  const float* bhh = (const float*)d_in[4];
  const float* Wfc = (const float*)d_in[5];
  const float* bfc = (const float*)d_in[6];
  float* out = (float*)d_out;

  char* ws = (char*)d_ws;
  unsigned int*   xproj = (unsigned int*)ws;                         // 128 MB (f16 pairs)
  unsigned short* h_all = (unsigned short*)(ws + 134217728);         // 32 MB (f16)
  unsigned int*   whhT  = (unsigned int*)(ws + 134217728 + 33554432);// 512 KB (chunked)
  unsigned int*   wfc16 = whhT + 131072;                             // 32 KB
  float*          bsum  = (float*)(wfc16 + 8192);                    // 4 KB

  prep_kernel<<<548, 256, 0, stream>>>(Whh, Wfc, bih, bhh, whhT, wfc16, bsum);
  dim3 gb(512, 16);
  xproj_kernel<<<gb, 256, 0, stream>>>(x, Wih, bsum, xproj);
  int dyn = (GOFF + 1024) * 4;   // 136,192 B dynamic LDS
  hipFuncSetAttribute((const void*)lstm_kernel, hipFuncAttributeMaxDynamicSharedMemorySize, dyn);
  lstm_kernel<<<32, 1024, dyn, stream>>>(whhT, xproj, h_all);
  fc_softmax_kernel<<<4096, 1024, 0, stream>>>(h_all, wfc16, bfc, out);
}

// Round 10
// 3052.692 us; speedup vs baseline: 3.1732x; 1.1718x over previous
//
#include <hip/hip_runtime.h>
#include <hip/hip_bf16.h>
#include <hip/hip_fp16.h>

typedef _Float16 v2h __attribute__((ext_vector_type(2)));

__device__ __forceinline__ float fdot2u(unsigned int a, unsigned int b, float c){
  return __builtin_amdgcn_fdot2(__builtin_bit_cast(v2h, a), __builtin_bit_cast(v2h, b), c, false);
}
__device__ __forceinline__ unsigned int packh2(float a, float b){
  union{ _Float16 h[2]; unsigned int u; } z;
  z.h[0] = (_Float16)a; z.h[1] = (_Float16)b; return z.u;
}
__device__ __forceinline__ float h2f(unsigned short s){
  return (float)__builtin_bit_cast(_Float16, s);
}
__device__ __forceinline__ float sigf(float x){
  return __builtin_amdgcn_rcpf(1.0f + __builtin_amdgcn_exp2f(-1.44269504f*x));
}
__device__ __forceinline__ float tanhf_(float x){
  return 2.0f*__builtin_amdgcn_rcpf(1.0f + __builtin_amdgcn_exp2f(-2.88539008f*x)) - 1.0f;
}
// quad_perm [1,0,3,2]: swap lane pairs (p0<->p1) — pure VALU
__device__ __forceinline__ float dpp_xor1(float x){
  return __builtin_bit_cast(float,
    __builtin_amdgcn_mov_dpp(__builtin_bit_cast(int, x), 0xB1, 0xF, 0xF, true));
}

// ---------------- Kernel A: weight conversion (K-half chunk layout) ----------------
// whhT3 uint4 index = (g*16+j)*512 + (u*2+p), dword l:
//   holds W_hh[g*256+u][k] pair for dword d = p*64 + j*4 + l (k = 2d, 2d+1).
__global__ void prep_kernel(const float* __restrict__ Whh, const float* __restrict__ Wfc,
                            const float* __restrict__ bih, const float* __restrict__ bhh,
                            unsigned int* __restrict__ whhT3, unsigned int* __restrict__ wfc16,
                            float* __restrict__ bsum){
  int i = blockIdx.x*256 + threadIdx.x;
  if (i < 131072){                       // W_hh (1024 x 256) f32 -> f16 pair dwords
    int r = i >> 7, d = i & 127;
    int g = r >> 8, u = r & 255;
    int p = (d >> 6) & 1, j = (d >> 2) & 15, l = d & 3;
    whhT3[(size_t)((g*16+j)*512 + u*2 + p)*4 + l] = packh2(Whh[r*256 + 2*d], Whh[r*256 + 2*d + 1]);
  } else if (i < 139264){                // W_fc (64 x 256) -> (64 x 128)
    int j = i - 131072; int o = j >> 7, d = j & 127;
    wfc16[j] = packh2(Wfc[o*256 + 2*d], Wfc[o*256 + 2*d + 1]);
  } else if (i < 140288){                // bsum = b_ih + b_hh
    int g = i - 139264;
    bsum[g] = bih[g] + bhh[g];
  }
}

// ---------------- Kernel B: x_proj = x @ W_ih^T + bsum (f16 out) ----------------
#define XS 68
__global__ __launch_bounds__(256) void xproj_kernel(const float* __restrict__ x,
                          const float* __restrict__ Wih,
                          const float* __restrict__ bsum, unsigned int* __restrict__ xproj){
  __shared__ unsigned int lx[128*XS];
  __shared__ unsigned int lw[64*XS];
  __shared__ float lb[64];
  int t  = threadIdx.x;
  int bt0 = blockIdx.x*128, g0 = blockIdx.y*64;
  int rr = t >> 4, cc = t & 15;
  #pragma unroll
  for (int it=0; it<8; ++it){
    int row = rr + it*16;
    const float4* s = (const float4*)(x + (size_t)(bt0+row)*128 + cc*8);
    float4 a = s[0], b = s[1];
    uint4 w; w.x=packh2(a.x,a.y); w.y=packh2(a.z,a.w); w.z=packh2(b.x,b.y); w.w=packh2(b.z,b.w);
    *(uint4*)&lx[row*XS + cc*4] = w;
  }
  #pragma unroll
  for (int it=0; it<4; ++it){
    int row = rr + it*16;
    const float4* s = (const float4*)(Wih + (size_t)(g0+row)*128 + cc*8);
    float4 a = s[0], b = s[1];
    uint4 w; w.x=packh2(a.x,a.y); w.y=packh2(a.z,a.w); w.z=packh2(b.x,b.y); w.w=packh2(b.z,b.w);
    *(uint4*)&lw[row*XS + cc*4] = w;
  }
  if (t < 64) lb[t] = bsum[g0 + t];
  __syncthreads();

  float acc[8][4];
  #pragma unroll
  for (int j=0;j<8;++j)
    #pragma unroll
    for (int i=0;i<4;++i) acc[j][i]=0.f;

  #pragma unroll
  for (int d4=0; d4<16; ++d4){
    uint4 wv[4], xv[8];
    #pragma unroll
    for (int i=0;i<4;++i) wv[i] = *(const uint4*)&lw[(cc*4+i)*XS + d4*4];
    #pragma unroll
    for (int j=0;j<8;++j) xv[j] = *(const uint4*)&lx[(rr*8+j)*XS + d4*4];
    #pragma unroll
    for (int j=0;j<8;++j){
      #pragma unroll
      for (int i=0;i<4;++i){
        float a = acc[j][i];
        a = fdot2u(xv[j].x, wv[i].x, a);
        a = fdot2u(xv[j].y, wv[i].y, a);
        a = fdot2u(xv[j].z, wv[i].z, a);
        a = fdot2u(xv[j].w, wv[i].w, a);
        acc[j][i] = a;
      }
    }
  }
  #pragma unroll
  for (int j=0;j<8;++j){
    int bt = bt0 + rr*8 + j;
    uint2 o2;
    o2.x = packh2(acc[j][0]+lb[cc*4+0], acc[j][1]+lb[cc*4+1]);
    o2.y = packh2(acc[j][2]+lb[cc*4+2], acc[j][3]+lb[cc*4+3]);
    *(uint2*)&xproj[(size_t)bt*512 + (g0>>1) + cc*2] = o2;
  }
}

// ---------------- Kernel C: recurrent LSTM (512 thr, K-half split, padded h) ----------------
// 512 threads/WG (8 waves, 2/SIMD -> 256 unified regs), 1 WG/batch.
// Thread t = u*2+p: ALL 4 gates of unit u over K-half p (64 h-dwords).
// Weights: chunks j=0..12 per gate in regs (208 dw), j=13..15 streamed from
// LDS ([group][gate][thread], conflict-free b128; base laundered vs LICM;
// serial load-group-then-consume keeps only 20 temp dwords live).
// h: double-buffered, PADDED halves (stride 68 dw): p=0 reads banks 4j..4j+3,
// p=1 reads 4j+4..4j+7 -> disjoint; writes p==0 lanes, consecutive u ->
// conflict-free. x_proj: 2 loads/thread, mask-fmaf inject (gate 2p, 2p+1).
// Pair-reduce: one quad_perm DPP add per gate. ONE barrier per step.
#define WRJ 13
#define WLJ 3
#define HOFF (4*WLJ*512*4)           // dword offset of h double-buffer (24576)

extern "C" __global__ void __launch_bounds__(512,2) lstm_kernel(
    const unsigned int* __restrict__ whhT3, const unsigned int* __restrict__ xproj,
    unsigned short* __restrict__ h_all)
{
  extern __shared__ unsigned int lds[];
  uint4* lw4 = (uint4*)lds;
  unsigned short* lds16 = (unsigned short*)lds;
  const int t = threadIdx.x;
  const int u = t >> 1, p = t & 1;
  const int b = blockIdx.x;

  const uint4* wsrc = (const uint4*)whhT3;
  uint4 w0[WRJ], w1[WRJ], w2[WRJ], w3[WRJ];
  #pragma unroll
  for (int j=0; j<WRJ; ++j){
    w0[j] = wsrc[(0*16+j)*512 + t];
    w1[j] = wsrc[(1*16+j)*512 + t];
    w2[j] = wsrc[(2*16+j)*512 + t];
    w3[j] = wsrc[(3*16+j)*512 + t];
  }
  #pragma unroll
  for (int jj=0; jj<WLJ; ++jj)
    #pragma unroll
    for (int g=0; g<4; ++g)
      lw4[(jj*4+g)*512 + t] = wsrc[(g*16+WRJ+jj)*512 + t];
  if (t < 272) lds[HOFF + t] = 0u;   // zero both padded h buffers (2 x 136 dw)

  const float mp = (p==0) ? 1.f : 0.f;
  const float mq = 1.f - mp;
  const unsigned short* xpb = (const unsigned short*)xproj + (size_t)b*2048*1024;
  // p=0 lane: gates 0,1 rows (u, 256+u); p=1 lane: gates 2,3 rows (512+u, 768+u)
  const int xoffA = p*512 + u, xoffB = p*512 + 256 + u;
  unsigned short xnA = xpb[xoffA], xnB = xpb[xoffB];
  float c = 0.f;
  unsigned short* hout = h_all + (size_t)b*2048*256 + u;
  __syncthreads();

  for (int tt=0; tt<2048; ++tt){
    const int cur = tt & 1;
    float xvA = h2f(xnA), xvB = h2f(xnB);
    int tn = (tt+1 < 2048) ? tt+1 : 2047;
    xnA = xpb[(size_t)tn*1024 + xoffA];
    xnB = xpb[(size_t)tn*1024 + xoffB];

    const unsigned int* hb = lds + HOFF + cur*136 + p*68;
    // launder LDS weight base: defeat LICM hoisting 48 dwords into registers
    int zoff = 0;
    asm volatile("" : "+v"(zoff));
    const uint4* lwl = lw4 + zoff;

    float A0=0.f, A1=0.f, A2=0.f, A3=0.f;
    #pragma unroll
    for (int j=0; j<WRJ; ++j){
      uint4 h4 = *(const uint4*)(hb + j*4);
      A0 = fdot2u(w0[j].x, h4.x, A0); A0 = fdot2u(w0[j].y, h4.y, A0);
      A0 = fdot2u(w0[j].z, h4.z, A0); A0 = fdot2u(w0[j].w, h4.w, A0);
      A1 = fdot2u(w1[j].x, h4.x, A1); A1 = fdot2u(w1[j].y, h4.y, A1);
      A1 = fdot2u(w1[j].z, h4.z, A1); A1 = fdot2u(w1[j].w, h4.w, A1);
      A2 = fdot2u(w2[j].x, h4.x, A2); A2 = fdot2u(w2[j].y, h4.y, A2);
      A2 = fdot2u(w2[j].z, h4.z, A2); A2 = fdot2u(w2[j].w, h4.w, A2);
      A3 = fdot2u(w3[j].x, h4.x, A3); A3 = fdot2u(w3[j].y, h4.y, A3);
      A3 = fdot2u(w3[j].z, h4.z, A3); A3 = fdot2u(w3[j].w, h4.w, A3);
    }
    // streamed chunks: serial load-group-then-consume (small temp footprint)
    #pragma unroll
    for (int jj=0; jj<WLJ; ++jj){
      uint4 h4 = *(const uint4*)(hb + (WRJ+jj)*4);
      uint4 s0 = lwl[(jj*4+0)*512 + t];
      uint4 s1 = lwl[(jj*4+1)*512 + t];
      uint4 s2 = lwl[(jj*4+2)*512 + t];
      uint4 s3 = lwl[(jj*4+3)*512 + t];
      A0 = fdot2u(s0.x, h4.x, A0); A0 = fdot2u(s0.y, h4.y, A0);
      A0 = fdot2u(s0.z, h4.z, A0); A0 = fdot2u(s0.w, h4.w, A0);
      A1 = fdot2u(s1.x, h4.x, A1); A1 = fdot2u(s1.y, h4.y, A1);
      A1 = fdot2u(s1.z, h4.z, A1); A1 = fdot2u(s1.w, h4.w, A1);
      A2 = fdot2u(s2.x, h4.x, A2); A2 = fdot2u(s2.y, h4.y, A2);
      A2 = fdot2u(s2.z, h4.z, A2); A2 = fdot2u(s2.w, h4.w, A2);
      A3 = fdot2u(s3.x, h4.x, A3); A3 = fdot2u(s3.y, h4.y, A3);
      A3 = fdot2u(s3.z, h4.z, A3); A3 = fdot2u(s3.w, h4.w, A3);
    }

    // inject x_proj pre-acts exactly once per gate (masked by lane role)
    A0 = fmaf(mp, xvA, A0); A1 = fmaf(mp, xvB, A1);
    A2 = fmaf(mq, xvA, A2); A3 = fmaf(mq, xvB, A3);
    // pair-reduce over K-halves: one DPP add per gate
    A0 += dpp_xor1(A0); A1 += dpp_xor1(A1);
    A2 += dpp_xor1(A2); A3 += dpp_xor1(A3);

    float gi = sigf(A0);
    float gf = sigf(A1);
    float gg = tanhf_(A2);
    float go = sigf(A3);
    c = gf*c + gi*gg;
    float h = go * tanhf_(c);
    unsigned short hh = __builtin_bit_cast(unsigned short, (_Float16)h);
    if (p == 0){
      // padded slot: u<128 -> u ; u>=128 -> u+8 (pad dwords 64..67)
      lds16[(HOFF + (cur^1)*136)*2 + u + ((u>>7)<<3)] = hh;
      hout[(size_t)tt*256] = hh;                 // h_all for fc phase
    }
    __syncthreads();
  }
}

// ---------------- Kernel D: logits = h @ W_fc^T + b_fc ; softmax over O=64 ----------------
__global__ __launch_bounds__(1024) void fc_softmax_kernel(const unsigned short* __restrict__ h_all,
      const unsigned int* __restrict__ wfc16, const float* __restrict__ bfc,
      float* __restrict__ out){
  __shared__ unsigned int lwf[64*132];
  __shared__ unsigned int lh[16*132];
  int t = threadIdx.x;
  int bt0 = blockIdx.x*16;
  {
    const uint4* s = (const uint4*)(wfc16 + (size_t)t*8);
    uint4 a = s[0], b = s[1];
    unsigned int* dst = &lwf[(t>>4)*132 + (t&15)*8];
    *(uint4*)dst = a; *(uint4*)(dst+4) = b;
  }
  {
    int row = t>>6, col = (t&63)*2;
    const unsigned int* hsrc = (const unsigned int*)h_all;
    uint2 v = *(const uint2*)(hsrc + (size_t)(bt0+row)*128 + col);
    *(uint2*)&lh[row*132 + col] = v;
  }
  __syncthreads();
  int w = t>>6, o = t&63;
  int bt = bt0 + w;
  float acc = bfc[o];
  #pragma unroll
  for (int d4=0; d4<32; ++d4){
    uint4 hq = *(const uint4*)&lh[w*132 + d4*4];
    uint4 wq = *(const uint4*)&lwf[o*132 + d4*4];
    acc = fdot2u(wq.x, hq.x, acc);
    acc = fdot2u(wq.y, hq.y, acc);
    acc = fdot2u(wq.z, hq.z, acc);
    acc = fdot2u(wq.w, hq.w, acc);
  }
  float m = acc;
  #pragma unroll
  for (int off=32; off>=1; off>>=1) m = fmaxf(m, __shfl_xor(m, off));
  float e = __builtin_amdgcn_exp2f(1.44269504f*(acc - m));
  float s = e;
  #pragma unroll
  for (int off=32; off>=1; off>>=1) s += __shfl_xor(s, off);
  out[(size_t)bt*64 + o] = e * __builtin_amdgcn_rcpf(s);
}

// ---------------- launch ----------------
extern "C" void kernel_launch(void* const* d_in, const int* in_sizes, int n_in,
                              void* d_out, int out_size, void* d_ws, size_t ws_size,
                              hipStream_t stream){
  const float* x   = (const float*)d_in[0];
  const float* Wih = (const float*)d_in[1];
  const float* Whh = (const float*)d_in[2];
  const float* bih = (const float*)d_in[3];
  const float* bhh = (const float*)d_in[4];
  const float* Wfc = (const float*)d_in[5];
  const float* bfc = (const float*)d_in[6];
  float* out = (float*)d_out;

  char* ws = (char*)d_ws;
  unsigned int*   xproj = (unsigned int*)ws;                         // 128 MB (f16 pairs)
  unsigned short* h_all = (unsigned short*)(ws + 134217728);         // 32 MB (f16)
  unsigned int*   whhT3 = (unsigned int*)(ws + 134217728 + 33554432);// 512 KB (chunked)
  unsigned int*   wfc16 = whhT3 + 131072;                            // 32 KB
  float*          bsum  = (float*)(wfc16 + 8192);                    // 4 KB

  prep_kernel<<<548, 256, 0, stream>>>(Whh, Wfc, bih, bhh, whhT3, wfc16, bsum);
  dim3 gb(512, 16);
  xproj_kernel<<<gb, 256, 0, stream>>>(x, Wih, bsum, xproj);
  int dyn = (HOFF + 272) * 4;   // 99,392 B dynamic LDS
  hipFuncSetAttribute((const void*)lstm_kernel, hipFuncAttributeMaxDynamicSharedMemorySize, dyn);
  lstm_kernel<<<32, 512, dyn, stream>>>(whhT3, xproj, h_all);
  fc_softmax_kernel<<<4096, 1024, 0, stream>>>(h_all, wfc16, bfc, out);
}